// Round 7
// baseline (189.883 us; speedup 1.0000x reference)
//
#include <hip/hip_runtime.h>

typedef __attribute__((ext_vector_type(8))) short short8;
typedef __attribute__((ext_vector_type(4))) float f32x4;

// ---- d_out scratch (float offsets), consumed before k2 overwrites:
//   xa_t  bf16[16777216] -> [0, 8388608) floats   tiled [16 bm][128 kt][256*32] swizzled
//   wb_t  bf16[ 4194304] -> [8388608, 10485760)   tiled [ 8 bn][128 kt][128*32] swizzled
//   plogit f32[4096*64]  -> [10485760, 10747904)  (kc x bn partials)
// ---- d_ws layout (bytes):
//   k_arr  int[4096]     [0, 16384)
//   sp_arr f32[4096]     [16384, 32768)
//   l1rows f64[4096]     [32768, 65536)
//
// Swizzle (both-sides, rule #21): element (row r, k kk) of a tile lives at
//   r*32 + ((kk>>3) ^ ((r>>1)&3))*8 + (kk&7)
// -> gl16 staging stays linear; ds_read_b128 applies the same XOR -> 2-way banks (free).

__device__ __forceinline__ unsigned short bf16rn(float f) {
    unsigned u = __float_as_uint(f);
    return (unsigned short)((u + 0x7fffu + ((u >> 16) & 1u)) >> 16);
}
__device__ __forceinline__ unsigned pack2(float lo, float hi) {
    return (unsigned)bf16rn(lo) | ((unsigned)bf16rn(hi) << 16);
}

__device__ __forceinline__ void gl16(const void* g, void* l) {
    __builtin_amdgcn_global_load_lds(
        (const __attribute__((address_space(1))) void*)g,
        (__attribute__((address_space(3))) void*)l, 16, 0, 0);
}

// ---------------- k0a: x (fp32 [4096][4096]) -> xa_t (bf16, K-tiled + swizzled)
// grid (64, 8): block = 64 x-rows by 16 k-tiles. Reads 128B/row segments, writes
// contiguous 1KB per wave.
__global__ __launch_bounds__(256) void k0a_cvtx(const float* __restrict__ x,
                                                unsigned short* __restrict__ xa_t)
{
    const int b = blockIdx.x;                 // 64 row-groups
    const int ksbase = blockIdx.y * 16;
    const int t = threadIdx.x;
    const int rr = t >> 2, q = t & 3;
    const int bm = b >> 2;
    const int rtile = (b & 3) * 64 + rr;
    const int kgp = q ^ ((rr >> 1) & 3);
    const size_t rowoff = (size_t)(b * 64 + rr) * 4096;

    #pragma unroll
    for (int i = 0; i < 16; i++) {
        const int ks = ksbase + i;
        const float* src = x + rowoff + ks * 32 + q * 8;
        float4 v0 = *(const float4*)src;
        float4 v1 = *(const float4*)(src + 4);
        uint4 o;
        o.x = pack2(v0.x, v0.y); o.y = pack2(v0.z, v0.w);
        o.z = pack2(v1.x, v1.y); o.w = pack2(v1.z, v1.w);
        *(uint4*)(xa_t + (size_t)(bm * 128 + ks) * 8192 + rtile * 32 + kgp * 8) = o;
    }
}

// ---------------- k0b: W1 [4096][1024] fp32 -> wb_t (bf16, transposed K-tiled + swizzled)
// grid 1024: block = one (bn, kt) tile (128 n x 32 k), via LDS transpose.
__global__ __launch_bounds__(256) void k0b_cvtw(const float* __restrict__ W1,
                                                unsigned short* __restrict__ wb_t)
{
    __shared__ float ls[32][128];
    const int bx = blockIdx.x;
    const int bn = bx >> 7, ks = bx & 127;
    const int t = threadIdx.x;

    #pragma unroll
    for (int i = 0; i < 4; i++) {
        int s = t + i * 256;                 // 1024 float4 slots
        int r = s >> 5, c4 = s & 31;
        *(float4*)&ls[r][c4 * 4] =
            *(const float4*)(W1 + (size_t)(ks * 32 + r) * 1024 + bn * 128 + c4 * 4);
    }
    __syncthreads();

    const int n = t >> 1, half = t & 1;
    #pragma unroll
    for (int kg2 = 0; kg2 < 2; kg2++) {
        const int kg = half * 2 + kg2;
        const int kgp = kg ^ ((n >> 1) & 3);
        uint4 o;
        o.x = pack2(ls[kg * 8 + 0][n], ls[kg * 8 + 1][n]);
        o.y = pack2(ls[kg * 8 + 2][n], ls[kg * 8 + 3][n]);
        o.z = pack2(ls[kg * 8 + 4][n], ls[kg * 8 + 5][n]);
        o.w = pack2(ls[kg * 8 + 6][n], ls[kg * 8 + 7][n]);
        *(uint4*)(wb_t + (size_t)(bn * 128 + ks) * 4096 + n * 32 + kgp * 8) = o;
    }
}

// ---------------- k1est: bf16 MFMA partial logits — BM=256 x BN=128, split-K(8)
// 512 thr = 8 waves (4m x 2n), wave tile 64x64, BK=32 double-buffered (48KB LDS).
// Staging is fully contiguous 16KB(A)+8KB(B) gl16 streams from the tiled scratch.
__global__ __launch_bounds__(512, 4) void k1est(const unsigned short* __restrict__ xa_t,
                                                const unsigned short* __restrict__ wb_t,
                                                const float* __restrict__ b1,
                                                const float* __restrict__ W2,
                                                float* __restrict__ plogit)
{
    __shared__ alignas(16) unsigned short Ab[2][8192];   // 2 x 16KB
    __shared__ alignas(16) unsigned short Bb[2][4096];   // 2 x 8KB

    const int bid = blockIdx.x;
    const int wgid = (bid & 7) * 128 + (bid >> 3);   // 1024 % 8 == 0, bijective
    const int kc = wgid >> 7;                        // 0..7
    const int rem = wgid & 127;
    const int bm = rem >> 3, bn = rem & 7;           // 16 x 8
    const int m0 = bm * 256, n0 = bn * 128;
    const int tid = threadIdx.x;
    const int l = tid & 63, w = tid >> 6;
    const int wm = w >> 1, wn = w & 1;
    const int arow = l & 15, kg = l >> 4;
    const int kgs = kg ^ ((arow >> 1) & 3);          // swizzled k-group (rows: bits1-2 = arow bits1-2)

    const unsigned short* abase = xa_t + (size_t)bm * 128 * 8192;
    const unsigned short* bbase = wb_t + (size_t)bn * 128 * 4096;

    f32x4 acc[4][4];
    #pragma unroll
    for (int i = 0; i < 4; i++)
        #pragma unroll
        for (int j = 0; j < 4; j++) acc[i][j] = (f32x4)0.0f;

    // prologue: stage k-tile kc*16 into buffer 0 (lane-linear source AND dest)
    {
        const size_t at = (size_t)(kc * 16) * 8192;
        const size_t bt = (size_t)(kc * 16) * 4096;
        gl16(abase + at + (size_t)tid * 8,         &Ab[0][tid * 8]);
        gl16(abase + at + (size_t)(512 + tid) * 8, &Ab[0][(512 + tid) * 8]);
        gl16(bbase + bt + (size_t)tid * 8,         &Bb[0][tid * 8]);
    }
    __syncthreads();

    for (int t = 0; t < 16; t++) {
        const int cur = t & 1;
        if (t < 15) {
            const size_t at = (size_t)(kc * 16 + t + 1) * 8192;
            const size_t bt = (size_t)(kc * 16 + t + 1) * 4096;
            gl16(abase + at + (size_t)tid * 8,         &Ab[cur ^ 1][tid * 8]);
            gl16(abase + at + (size_t)(512 + tid) * 8, &Ab[cur ^ 1][(512 + tid) * 8]);
            gl16(bbase + bt + (size_t)tid * 8,         &Bb[cur ^ 1][tid * 8]);
        }
        short8 af[4], bf[4];
        #pragma unroll
        for (int mf = 0; mf < 4; mf++) {
            const int row = wm * 64 + mf * 16 + arow;
            af[mf] = *(const short8*)&Ab[cur][row * 32 + kgs * 8];
        }
        #pragma unroll
        for (int nf = 0; nf < 4; nf++) {
            const int n = wn * 64 + nf * 16 + arow;
            bf[nf] = *(const short8*)&Bb[cur][n * 32 + kgs * 8];
        }
        #pragma unroll
        for (int mf = 0; mf < 4; mf++)
            #pragma unroll
            for (int nf = 0; nf < 4; nf++)
                acc[mf][nf] = __builtin_amdgcn_mfma_f32_16x16x32_bf16(
                    af[mf], bf[nf], acc[mf][nf], 0, 0, 0);
        __syncthreads();
    }

    // epilogue: h = acc + b1, relu, dot W2 over this wave's 64 cols (K-chunk partial)
    // C/D layout (m89): col = lane&15 (N idx), row = (lane>>4)*4 + i (M idx)
    #pragma unroll
    for (int mf = 0; mf < 4; mf++) {
        #pragma unroll
        for (int i = 0; i < 4; i++) {
            float p = 0.0f;
            #pragma unroll
            for (int nf = 0; nf < 4; nf++) {
                int n = n0 + wn * 64 + nf * 16 + arow;
                float h = acc[mf][nf][i] + b1[n];
                if (h > 0.0f) p += h * W2[n];
            }
            #pragma unroll
            for (int o = 1; o < 16; o <<= 1) p += __shfl_xor(p, o, 64);
            if (arow == 0) {
                int row = m0 + wm * 64 + mf * 16 + kg * 4 + i;
                atomicAdd(&plogit[(size_t)row * 64 + kc * 8 + bn], p);
            }
        }
    }
}

// ---------------- k1z: zero plogit (atomicAdd accumulation target)
__global__ __launch_bounds__(256) void k1z_zero(float* __restrict__ plogit)
{
    plogit[blockIdx.x * 256 + threadIdx.x] = 0.0f;
}

// ---------------- k1b: per-row logit -> sigmoid -> sparsity/k (sums 64 partials)
__global__ __launch_bounds__(256) void k1b_k(const float* __restrict__ plogit,
                                             const float* __restrict__ b2,
                                             int* __restrict__ k_arr,
                                             float* __restrict__ sp_arr)
{
    int row = blockIdx.x * 256 + threadIdx.x;
    float lg = 0.0f;
    #pragma unroll
    for (int t = 0; t < 64; t++) lg += plogit[(size_t)row * 64 + t];
    double s  = 1.0 / (1.0 + exp(-(double)(lg + b2[0])));
    double sp = 0.05 + 0.25 * s;
    int k = (int)rint(4096.0 * (1.0 - sp));
    if (k < 1) k = 1;
    if (k > 4096) k = 4096;
    k_arr[row] = k;
    sp_arr[row] = (float)sp;
}

// ---------------- k2: per-row radix-select threshold + all big outputs
__global__ __launch_bounds__(256) void k2_row(const float* __restrict__ x,
                                              const int* __restrict__ k_arr,
                                              const float* __restrict__ sp_arr,
                                              float* __restrict__ out_sparse,
                                              float* __restrict__ out_mask,
                                              float* __restrict__ out_spars,
                                              float* __restrict__ out_actual,
                                              double* __restrict__ l1rows)
{
    __shared__ unsigned bits[4096];
    __shared__ unsigned hist[256];
    __shared__ unsigned wsum[4];
    __shared__ int cnt_w[4];
    __shared__ double l1_w[4];
    __shared__ int sel_s;
    __shared__ unsigned selexc_s;

    const int row = blockIdx.x;
    const int tid = threadIdx.x;
    const int lane = tid & 63, wid = tid >> 6;
    const float* xr = x + (size_t)row * 4096;

    for (int i = tid; i < 1024; i += 256) {
        uint4 v = ((const uint4*)xr)[i];
        bits[i * 4 + 0] = v.x;
        bits[i * 4 + 1] = v.y;
        bits[i * 4 + 2] = v.z;
        bits[i * 4 + 3] = v.w;
    }
    if (tid == 0) out_spars[row] = sp_arr[row];
    __syncthreads();

    int krem = k_arr[row];
    unsigned prefix = 0;
    for (int pass = 0; pass < 4; pass++) {
        int shift = 24 - pass * 8;
        hist[tid] = 0;
        __syncthreads();
        for (int i = tid; i < 4096; i += 256) {
            unsigned a = bits[i] & 0x7fffffffu;
            bool ok = (pass == 0) || ((a >> (shift + 8)) == prefix);
            if (ok) atomicAdd(&hist[(a >> shift) & 255u], 1u);
        }
        __syncthreads();
        unsigned v = hist[tid];
        unsigned sc = v;
        #pragma unroll
        for (int o = 1; o < 64; o <<= 1) {
            unsigned n = __shfl_up(sc, o, 64);
            if (lane >= o) sc += n;
        }
        if (lane == 63) wsum[wid] = sc;
        __syncthreads();
        unsigned off = 0;
        for (int ww = 0; ww < wid; ww++) off += wsum[ww];
        sc += off;
        unsigned exc = sc - v;
        if ((int)sc >= krem && (int)exc < krem) { sel_s = tid; selexc_s = exc; }
        __syncthreads();
        prefix = (prefix << 8) | (unsigned)sel_s;
        krem -= (int)selexc_s;
        __syncthreads();
    }
    const unsigned thr = prefix;   // bit pattern of kth smallest |x|

    int cnt = 0;
    double l1 = 0.0;
    float* os = out_sparse + (size_t)row * 4096;
    float* om = out_mask + (size_t)row * 4096;
    for (int i = tid; i < 1024; i += 256) {
        float4 sv, mv;
        #pragma unroll
        for (int j = 0; j < 4; j++) {
            unsigned b = bits[i * 4 + j];
            unsigned a = b & 0x7fffffffu;
            bool m = a > thr;
            (&sv.x)[j] = m ? __uint_as_float(b) : 0.0f;
            (&mv.x)[j] = m ? 1.0f : 0.0f;
            if (m) { cnt++; l1 += (double)__uint_as_float(a); }
        }
        ((float4*)os)[i] = sv;
        ((float4*)om)[i] = mv;
    }
    #pragma unroll
    for (int o = 32; o > 0; o >>= 1) {
        cnt += __shfl_down(cnt, o, 64);
        l1  += __shfl_down(l1,  o, 64);
    }
    if (lane == 0) { cnt_w[wid] = cnt; l1_w[wid] = l1; }
    __syncthreads();
    if (tid == 0) {
        int c    = cnt_w[0] + cnt_w[1] + cnt_w[2] + cnt_w[3];
        double l = l1_w[0] + l1_w[1] + l1_w[2] + l1_w[3];
        out_actual[row] = (float)c / 4096.0f;
        l1rows[row] = l;
    }
}

// ---------------- k3: deterministic l1 mean (f64)
__global__ __launch_bounds__(256) void k3_l1(const double* __restrict__ l1rows,
                                             float* __restrict__ out_l1)
{
    __shared__ double sm[256];
    int tid = threadIdx.x;
    double s = 0.0;
    for (int i = tid; i < 4096; i += 256) s += l1rows[i];
    sm[tid] = s;
    __syncthreads();
    for (int st = 128; st > 0; st >>= 1) {
        if (tid < st) sm[tid] += sm[tid + st];
        __syncthreads();
    }
    if (tid == 0) out_l1[0] = (float)(sm[0] / 4096.0);
}

extern "C" void kernel_launch(void* const* d_in, const int* in_sizes, int n_in,
                              void* d_out, int out_size, void* d_ws, size_t ws_size,
                              hipStream_t stream)
{
    const float* x  = (const float*)d_in[0];
    const float* W1 = (const float*)d_in[1];
    const float* b1 = (const float*)d_in[2];
    const float* W2 = (const float*)d_in[3];
    const float* b2 = (const float*)d_in[4];

    float* out        = (float*)d_out;
    float* out_sparse = out;                       // [4096,4096]
    float* out_mask   = out + 16777216;            // [4096,4096]
    float* out_spars  = out + 33554432;            // [4096,1]
    float* out_actual = out + 33558528;            // [4096]
    float* out_l1     = out + 33562624;            // [1]

    // big scratch inside d_out's sparse region (consumed before k2 writes it)
    unsigned short* xa_t = (unsigned short*)(out);               // 32MB
    unsigned short* wb_t = (unsigned short*)(out + 8388608);     // 8MB
    float*          plogit = out + 10485760;                     // 1MB, [4096][64]

    // small hot arrays in d_ws (read by k2/k3 -> must not alias outputs)
    char* ws = (char*)d_ws;
    int*    k_arr  = (int*)(ws);               // 16KB
    float*  sp_arr = (float*)(ws + 16384);     // 16KB
    double* l1rows = (double*)(ws + 32768);    // 32KB

    k0a_cvtx<<<dim3(64, 8), 256, 0, stream>>>(x, xa_t);
    k0b_cvtw<<<1024, 256, 0, stream>>>(W1, wb_t);
    k1z_zero<<<1024, 256, 0, stream>>>(plogit);
    k1est<<<1024, 512, 0, stream>>>(xa_t, wb_t, b1, W2, plogit);
    k1b_k<<<16, 256, 0, stream>>>(plogit, b2, k_arr, sp_arr);
    k2_row<<<4096, 256, 0, stream>>>(x, k_arr, sp_arr, out_sparse, out_mask,
                                     out_spars, out_actual, l1rows);
    k3_l1<<<1, 256, 0, stream>>>(l1rows, out_l1);
}

// Round 8
// 182.616 us; speedup vs baseline: 1.0398x; 1.0398x over previous
//
#include <hip/hip_runtime.h>
#include <hip/hip_fp8.h>

typedef __attribute__((ext_vector_type(4))) float f32x4;

// ---- d_out scratch (float offsets), consumed by k1est/k1r before k2 overwrites:
//   xa_t  fp8[16777216B] -> floats [0, 4194304)        tiled [16 bm][128 kt][256*32] swz
//   wb_t  fp8[ 4194304B] -> floats [4194304, 5242880)  tiled [ 8 bn][128 kt][128*32] swz (W1*64)
//   hpartT f32[4][1024][4096] -> floats [5242880, 22020096)   raw h K-chunk partials, col-major
// ---- d_ws layout (bytes):
//   k_arr  int[4096]  [0,16384)   sp_arr f32[4096] [16384,32768)   l1rows f64[4096] [32768,65536)
//
// Swizzle (both sides, rule #21): tile element (row r, k kk) at byte
//   r*32 + ((kk>>3) ^ ((r>>1)&3))*8 + (kk&7)  -> gl16 staging linear, ds_read_b64 XORs same.

__device__ __forceinline__ unsigned char f2fp8(float f) {
    return (unsigned char)__hip_cvt_float_to_fp8(f, __HIP_SATFINITE, __HIP_E4M3);
}

__device__ __forceinline__ void gl16(const void* g, void* l) {
    __builtin_amdgcn_global_load_lds(
        (const __attribute__((address_space(1))) void*)g,
        (__attribute__((address_space(3))) void*)l, 16, 0, 0);
}

// ---------------- k0a: x (fp32 [4096][4096]) -> xa_t (fp8 e4m3, K-tiled + swizzled)
__global__ __launch_bounds__(256) void k0a_cvtx(const float* __restrict__ x,
                                                unsigned char* __restrict__ xa_t)
{
    const int b = blockIdx.x;                 // 64-row group, 0..63
    const int ktbase = blockIdx.y * 16;       // 8 y-blocks x 16 kt
    const int t = threadIdx.x;
    const int rr = t >> 2, q = t & 3;
    const int bm = b >> 2;
    const int rtile = (b & 3) * 64 + rr;      // (rtile>>1)&3 == (rr>>1)&3
    const int kgp = q ^ ((rr >> 1) & 3);
    const size_t rowoff = (size_t)(b * 64 + rr) * 4096;

    #pragma unroll
    for (int i = 0; i < 16; i++) {
        const int kt = ktbase + i;
        const float* src = x + rowoff + kt * 32 + q * 8;
        float4 v0 = *(const float4*)src;
        float4 v1 = *(const float4*)(src + 4);
        union { unsigned char c[8]; uint2 u; } o;
        o.c[0] = f2fp8(v0.x); o.c[1] = f2fp8(v0.y);
        o.c[2] = f2fp8(v0.z); o.c[3] = f2fp8(v0.w);
        o.c[4] = f2fp8(v1.x); o.c[5] = f2fp8(v1.y);
        o.c[6] = f2fp8(v1.z); o.c[7] = f2fp8(v1.w);
        *(uint2*)(xa_t + (size_t)(bm * 128 + kt) * 8192 + rtile * 32 + kgp * 8) = o.u;
    }
}

// ---------------- k0b: W1 [4096][1024] fp32 -> wb_t (fp8 of 64*W1, transposed tiled + swz)
__global__ __launch_bounds__(256) void k0b_cvtw(const float* __restrict__ W1,
                                                unsigned char* __restrict__ wb_t)
{
    __shared__ float ls[32][128];
    const int bx = blockIdx.x;                // 1024 = 8 bn x 128 kt
    const int bn = bx >> 7, kt = bx & 127;
    const int t = threadIdx.x;

    #pragma unroll
    for (int i = 0; i < 4; i++) {
        int s = t + i * 256;                  // 1024 float4 slots
        int r = s >> 5, c4 = s & 31;
        *(float4*)&ls[r][c4 * 4] =
            *(const float4*)(W1 + (size_t)(kt * 32 + r) * 1024 + bn * 128 + c4 * 4);
    }
    __syncthreads();

    const int n = t >> 1, half = t & 1;
    #pragma unroll
    for (int kg2 = 0; kg2 < 2; kg2++) {
        const int kg = half * 2 + kg2;
        const int kgp = kg ^ ((n >> 1) & 3);
        union { unsigned char c[8]; uint2 u; } o;
        #pragma unroll
        for (int j = 0; j < 8; j++) o.c[j] = f2fp8(ls[kg * 8 + j][n] * 64.0f);
        *(uint2*)(wb_t + (size_t)(bn * 128 + kt) * 4096 + n * 32 + kgp * 8) = o.u;
    }
}

// ---------------- k1est: fp8 MFMA raw h partials — BM=256 x BN=128, split-K(4), NO relu here
// 512 thr = 8 waves (4m x 2n), wave tile 64x64, BK=32 double-buffered (24KB LDS).
__global__ __launch_bounds__(512, 4) void k1est(const unsigned char* __restrict__ xa_t,
                                                const unsigned char* __restrict__ wb_t,
                                                float* __restrict__ hpartT)
{
    __shared__ alignas(16) unsigned char Ab[2][8192];   // 2 x 8KB
    __shared__ alignas(16) unsigned char Bb[2][4096];   // 2 x 4KB

    const int bid = blockIdx.x;
    const int wgid = (bid & 7) * 64 + (bid >> 3);   // 512 % 8 == 0, bijective
    const int kc = wgid >> 7;                       // 0..3
    const int rem = wgid & 127;
    const int bm = rem >> 3, bn = rem & 7;          // 16 x 8
    const int tid = threadIdx.x;
    const int l = tid & 63, w = tid >> 6;
    const int wm = w >> 1, wn = w & 1;
    const int arow = l & 15, kg = l >> 4;
    const int kgs = kg ^ ((arow >> 1) & 3);

    const unsigned char* abase = xa_t + (size_t)bm * 128 * 8192;
    const unsigned char* bbase = wb_t + (size_t)bn * 128 * 4096;

    f32x4 acc[4][4];
    #pragma unroll
    for (int i = 0; i < 4; i++)
        #pragma unroll
        for (int j = 0; j < 4; j++) acc[i][j] = (f32x4)0.0f;

    // prologue: stage kt = kc*32 into buffer 0 (lane-linear source AND dest)
    {
        const size_t at = (size_t)(kc * 32) * 8192;
        gl16(abase + at + (size_t)tid * 16, &Ab[0][tid * 16]);
        if (tid < 256) {
            const size_t bt = (size_t)(kc * 32) * 4096;
            gl16(bbase + bt + (size_t)tid * 16, &Bb[0][tid * 16]);
        }
    }
    __syncthreads();

    for (int t = 0; t < 32; t++) {
        const int cur = t & 1;
        if (t < 31) {
            const size_t at = (size_t)(kc * 32 + t + 1) * 8192;
            gl16(abase + at + (size_t)tid * 16, &Ab[cur ^ 1][tid * 16]);
            if (tid < 256) {
                const size_t bt = (size_t)(kc * 32 + t + 1) * 4096;
                gl16(bbase + bt + (size_t)tid * 16, &Bb[cur ^ 1][tid * 16]);
            }
        }
        long af[4], bf[4];
        #pragma unroll
        for (int mf = 0; mf < 4; mf++)
            af[mf] = *(const long*)&Ab[cur][(wm * 64 + mf * 16 + arow) * 32 + kgs * 8];
        #pragma unroll
        for (int nf = 0; nf < 4; nf++)
            bf[nf] = *(const long*)&Bb[cur][(wn * 64 + nf * 16 + arow) * 32 + kgs * 8];
        #pragma unroll
        for (int mf = 0; mf < 4; mf++)
            #pragma unroll
            for (int nf = 0; nf < 4; nf++)
                acc[mf][nf] = __builtin_amdgcn_mfma_f32_16x16x32_fp8_fp8(
                    af[mf], bf[nf], acc[mf][nf], 0, 0, 0);
        __syncthreads();
    }

    // store RAW partials (no b1, no relu) column-major: hpartT[kc][col][row]
    // C/D layout (m89): col = lane&15 (N idx), row = (lane>>4)*4 + i (M idx)
    const int m0 = bm * 256, n0 = bn * 128;
    float* hp = hpartT + (size_t)kc * 4194304;
    #pragma unroll
    for (int mf = 0; mf < 4; mf++) {
        #pragma unroll
        for (int nf = 0; nf < 4; nf++) {
            const int row = m0 + wm * 64 + mf * 16 + kg * 4;   // 4 consecutive rows
            const int col = n0 + wn * 64 + nf * 16 + arow;
            *(f32x4*)(hp + (size_t)col * 4096 + row) = acc[mf][nf];
        }
    }
}

// ---------------- k1r: sum K-chunks -> /64 -> +b1 -> relu -> dot W2 -> sigmoid -> k
// grid 128 blocks x 256 thr; block = 32 rows; thread (r = t&31, cq = t>>5 handles c ≡ cq mod 8)
__global__ __launch_bounds__(256) void k1r_logit(const float* __restrict__ hpartT,
                                                 const float* __restrict__ b1,
                                                 const float* __restrict__ W2,
                                                 const float* __restrict__ b2,
                                                 int* __restrict__ k_arr,
                                                 float* __restrict__ sp_arr)
{
    __shared__ float ps[32][8];
    const int row0 = blockIdx.x * 32;
    const int t = threadIdx.x;
    const int r = t & 31, cq = t >> 5;
    const int row = row0 + r;

    float p = 0.0f;
    for (int cb = 0; cb < 1024; cb += 8) {
        const int c = cb + cq;
        float v = 0.0f;
        #pragma unroll
        for (int kc = 0; kc < 4; kc++)
            v += hpartT[(size_t)kc * 4194304 + (size_t)c * 4096 + row];
        float h = v * 0.015625f + b1[c];     // undo W1*64 scale
        if (h > 0.0f) p += h * W2[c];
    }
    ps[r][cq] = p;
    __syncthreads();
    if (t < 32) {
        float lg = 0.0f;
        #pragma unroll
        for (int j = 0; j < 8; j++) lg += ps[t][j];
        double s  = 1.0 / (1.0 + exp(-(double)(lg + b2[0])));
        double sp = 0.05 + 0.25 * s;
        int k = (int)rint(4096.0 * (1.0 - sp));
        if (k < 1) k = 1;
        if (k > 4096) k = 4096;
        k_arr[row0 + t] = k;
        sp_arr[row0 + t] = (float)sp;
    }
}

// ---------------- k2: per-row radix-select threshold + all big outputs
__global__ __launch_bounds__(256) void k2_row(const float* __restrict__ x,
                                              const int* __restrict__ k_arr,
                                              const float* __restrict__ sp_arr,
                                              float* __restrict__ out_sparse,
                                              float* __restrict__ out_mask,
                                              float* __restrict__ out_spars,
                                              float* __restrict__ out_actual,
                                              double* __restrict__ l1rows)
{
    __shared__ unsigned bits[4096];
    __shared__ unsigned hist[256];
    __shared__ unsigned wsum[4];
    __shared__ int cnt_w[4];
    __shared__ double l1_w[4];
    __shared__ int sel_s;
    __shared__ unsigned selexc_s;

    const int row = blockIdx.x;
    const int tid = threadIdx.x;
    const int lane = tid & 63, wid = tid >> 6;
    const float* xr = x + (size_t)row * 4096;

    for (int i = tid; i < 1024; i += 256) {
        uint4 v = ((const uint4*)xr)[i];
        bits[i * 4 + 0] = v.x;
        bits[i * 4 + 1] = v.y;
        bits[i * 4 + 2] = v.z;
        bits[i * 4 + 3] = v.w;
    }
    if (tid == 0) out_spars[row] = sp_arr[row];
    __syncthreads();

    int krem = k_arr[row];
    unsigned prefix = 0;
    for (int pass = 0; pass < 4; pass++) {
        int shift = 24 - pass * 8;
        hist[tid] = 0;
        __syncthreads();
        for (int i = tid; i < 4096; i += 256) {
            unsigned a = bits[i] & 0x7fffffffu;
            bool ok = (pass == 0) || ((a >> (shift + 8)) == prefix);
            if (ok) atomicAdd(&hist[(a >> shift) & 255u], 1u);
        }
        __syncthreads();
        unsigned v = hist[tid];
        unsigned sc = v;
        #pragma unroll
        for (int o = 1; o < 64; o <<= 1) {
            unsigned n = __shfl_up(sc, o, 64);
            if (lane >= o) sc += n;
        }
        if (lane == 63) wsum[wid] = sc;
        __syncthreads();
        unsigned off = 0;
        for (int ww = 0; ww < wid; ww++) off += wsum[ww];
        sc += off;
        unsigned exc = sc - v;
        if ((int)sc >= krem && (int)exc < krem) { sel_s = tid; selexc_s = exc; }
        __syncthreads();
        prefix = (prefix << 8) | (unsigned)sel_s;
        krem -= (int)selexc_s;
        __syncthreads();
    }
    const unsigned thr = prefix;   // bit pattern of kth smallest |x|

    int cnt = 0;
    double l1 = 0.0;
    float* os = out_sparse + (size_t)row * 4096;
    float* om = out_mask + (size_t)row * 4096;
    for (int i = tid; i < 1024; i += 256) {
        float4 sv, mv;
        #pragma unroll
        for (int j = 0; j < 4; j++) {
            unsigned b = bits[i * 4 + j];
            unsigned a = b & 0x7fffffffu;
            bool m = a > thr;
            (&sv.x)[j] = m ? __uint_as_float(b) : 0.0f;
            (&mv.x)[j] = m ? 1.0f : 0.0f;
            if (m) { cnt++; l1 += (double)__uint_as_float(a); }
        }
        ((float4*)os)[i] = sv;
        ((float4*)om)[i] = mv;
    }
    #pragma unroll
    for (int o = 32; o > 0; o >>= 1) {
        cnt += __shfl_down(cnt, o, 64);
        l1  += __shfl_down(l1,  o, 64);
    }
    if (lane == 0) { cnt_w[wid] = cnt; l1_w[wid] = l1; }
    __syncthreads();
    if (tid == 0) {
        int c    = cnt_w[0] + cnt_w[1] + cnt_w[2] + cnt_w[3];
        double l = l1_w[0] + l1_w[1] + l1_w[2] + l1_w[3];
        out_actual[row] = (float)c / 4096.0f;
        l1rows[row] = l;
    }
}

// ---------------- k3: deterministic l1 mean (f64), 1024 threads
__global__ __launch_bounds__(1024) void k3_l1(const double* __restrict__ l1rows,
                                              float* __restrict__ out_l1)
{
    __shared__ double sm[1024];
    int tid = threadIdx.x;
    double s = l1rows[tid] + l1rows[tid + 1024] + l1rows[tid + 2048] + l1rows[tid + 3072];
    sm[tid] = s;
    __syncthreads();
    for (int st = 512; st > 0; st >>= 1) {
        if (tid < st) sm[tid] += sm[tid + st];
        __syncthreads();
    }
    if (tid == 0) out_l1[0] = (float)(sm[0] / 4096.0);
}

extern "C" void kernel_launch(void* const* d_in, const int* in_sizes, int n_in,
                              void* d_out, int out_size, void* d_ws, size_t ws_size,
                              hipStream_t stream)
{
    const float* x  = (const float*)d_in[0];
    const float* W1 = (const float*)d_in[1];
    const float* b1 = (const float*)d_in[2];
    const float* W2 = (const float*)d_in[3];
    const float* b2 = (const float*)d_in[4];

    float* out        = (float*)d_out;
    float* out_sparse = out;                       // [4096,4096]
    float* out_mask   = out + 16777216;            // [4096,4096]
    float* out_spars  = out + 33554432;            // [4096,1]
    float* out_actual = out + 33558528;            // [4096]
    float* out_l1     = out + 33562624;            // [1]

    // big scratch inside d_out (fully consumed by k1est/k1r before k2 writes)
    unsigned char* xa_t   = (unsigned char*)(out);             // 16MB fp8
    unsigned char* wb_t   = (unsigned char*)(out + 4194304);   // 4MB fp8
    float*         hpartT = out + 5242880;                     // 64MB f32 [4][1024][4096]

    // small hot arrays in d_ws (read by k2/k3 -> must not alias outputs)
    char* ws = (char*)d_ws;
    int*    k_arr  = (int*)(ws);               // 16KB
    float*  sp_arr = (float*)(ws + 16384);     // 16KB
    double* l1rows = (double*)(ws + 32768);    // 32KB

    k0a_cvtx<<<dim3(64, 8), 256, 0, stream>>>(x, xa_t);
    k0b_cvtw<<<1024, 256, 0, stream>>>(W1, wb_t);
    k1est<<<512, 512, 0, stream>>>(xa_t, wb_t, hpartT);
    k1r_logit<<<128, 256, 0, stream>>>(hpartT, b1, W2, b2, k_arr, sp_arr);
    k2_row<<<4096, 256, 0, stream>>>(x, k_arr, sp_arr, out_sparse, out_mask,
                                     out_spars, out_actual, l1rows);
    k3_l1<<<1, 1024, 0, stream>>>(l1rows, out_l1);
}

// Round 9
// 143.249 us; speedup vs baseline: 1.3255x; 1.2748x over previous
//
#include <hip/hip_runtime.h>
#include <hip/hip_fp8.h>

typedef __attribute__((ext_vector_type(4))) float f32x4;

// ---- d_out scratch (float offsets), consumed by k1est before k2 overwrites:
//   xa_t fp8[16777216B] -> floats [0, 4194304)        tiled [64 bm][128 kt][64 r][32 k] swz
//   wb_t fp8[ 4194304B] -> floats [4194304, 5242880)  tiled [ 8 bn][128 kt][128 n][32 k] swz (W1*64)
// ---- d_ws layout (bytes):
//   plogit f32[4096*8]  [0, 131072)      exact relu'd N-partials (unique writer)
//   k_arr  int[4096]    [131072, 147456)
//   sp_arr f32[4096]    [147456, 163840)
//   l1rows f64[4096]    [163840, 196608)
//
// Swizzle (both sides, rule #21): tile element (row r, k kk) at byte
//   r*32 + ((kk>>3) ^ ((r>>1)&3))*8 + (kk&7); staging is a pure linear copy,
//   MFMA ds_read applies the same XOR (kgs) -> <=2-way banks (free, m136).

__device__ __forceinline__ unsigned char f2fp8(float f) {
    return (unsigned char)__hip_cvt_float_to_fp8(f, __HIP_SATFINITE, __HIP_E4M3);
}

__device__ __forceinline__ void gl16(const void* g, void* l) {
    __builtin_amdgcn_global_load_lds(
        (const __attribute__((address_space(1))) void*)g,
        (__attribute__((address_space(3))) void*)l, 16, 0, 0);
}

// ---------------- k0a: x (fp32 [4096][4096]) -> xa_t (fp8 e4m3, 64-row K-tiled + swz)
__global__ __launch_bounds__(256) void k0a_cvtx(const float* __restrict__ x,
                                                unsigned char* __restrict__ xa_t)
{
    const int bm = blockIdx.x;                // 0..63 (64-row group)
    const int ktbase = blockIdx.y * 16;       // 8 y-blocks x 16 kt
    const int t = threadIdx.x;
    const int rr = t >> 2, q = t & 3;         // row 0..63, k-oct 0..3
    const int kgp = q ^ ((rr >> 1) & 3);
    const size_t rowoff = (size_t)(bm * 64 + rr) * 4096;

    #pragma unroll
    for (int i = 0; i < 16; i++) {
        const int kt = ktbase + i;
        const float* src = x + rowoff + kt * 32 + q * 8;
        float4 v0 = *(const float4*)src;
        float4 v1 = *(const float4*)(src + 4);
        union { unsigned char c[8]; uint2 u; } o;
        o.c[0] = f2fp8(v0.x); o.c[1] = f2fp8(v0.y);
        o.c[2] = f2fp8(v0.z); o.c[3] = f2fp8(v0.w);
        o.c[4] = f2fp8(v1.x); o.c[5] = f2fp8(v1.y);
        o.c[6] = f2fp8(v1.z); o.c[7] = f2fp8(v1.w);
        *(uint2*)(xa_t + ((size_t)(bm * 128 + kt) * 64 + rr) * 32 + kgp * 8) = o.u;
    }
}

// ---------------- k0b: W1 [4096][1024] fp32 -> wb_t (fp8 of 64*W1, transposed tiled + swz)
__global__ __launch_bounds__(256) void k0b_cvtw(const float* __restrict__ W1,
                                                unsigned char* __restrict__ wb_t)
{
    __shared__ float ls[32][128];
    const int bx = blockIdx.x;                // 1024 = 8 bn x 128 kt
    const int bn = bx >> 7, kt = bx & 127;
    const int t = threadIdx.x;

    #pragma unroll
    for (int i = 0; i < 4; i++) {
        int s = t + i * 256;                  // 1024 float4 slots
        int r = s >> 5, c4 = s & 31;
        *(float4*)&ls[r][c4 * 4] =
            *(const float4*)(W1 + (size_t)(kt * 32 + r) * 1024 + bn * 128 + c4 * 4);
    }
    __syncthreads();

    const int n = t >> 1, half = t & 1;
    #pragma unroll
    for (int kg2 = 0; kg2 < 2; kg2++) {
        const int kg = half * 2 + kg2;
        const int kgp = kg ^ ((n >> 1) & 3);
        union { unsigned char c[8]; uint2 u; } o;
        #pragma unroll
        for (int j = 0; j < 8; j++) o.c[j] = f2fp8(ls[kg * 8 + j][n] * 64.0f);
        *(uint2*)(wb_t + (size_t)(bn * 128 + kt) * 4096 + n * 32 + kgp * 8) = o.u;
    }
}

// ---------------- k1est: fp8 MFMA, BM=64 x BN=128, FULL K (exact relu), N-split partials.
// 256 thr = 4 waves, wave w owns rows w*16 (1 m-frag x 8 n-frags).
// Quad-buffered LDS (48KB), 2-tiles-ahead prefetch, counted vmcnt(6) — never drains
// to 0 in the loop (T3+T4). One s_barrier per step.
// XCD pinning: wgid=(bid&7)*64+(bid>>3), bn=wgid>>6 -> one bn (512KB W-slice) per XCD.
__global__ __launch_bounds__(256, 2) void k1est(const unsigned char* __restrict__ xa_t,
                                                const unsigned char* __restrict__ wb_t,
                                                const float* __restrict__ b1,
                                                const float* __restrict__ W2,
                                                float* __restrict__ plogit)
{
    __shared__ alignas(16) unsigned char Ab[4][4096];   // 4 bufs x (2 kt x 64 r x 32 k)
    __shared__ alignas(16) unsigned char Bb[4][8192];   // 4 bufs x (2 kt x 128 n x 32 k)

    const int bid = blockIdx.x;                      // 512 blocks
    const int wgid = (bid & 7) * 64 + (bid >> 3);    // bijective, XCD-chunked
    const int bn = wgid >> 6, bm = wgid & 63;        // bn 0..7 (one per XCD), bm 0..63
    const int tid = threadIdx.x;
    const int l = tid & 63, w = tid >> 6;
    const int arow = l & 15, kg = l >> 4;
    const int kgs = kg ^ ((arow >> 1) & 3);

    const unsigned char* abase = xa_t + (size_t)bm * 128 * 2048;   // 256KB slice
    const unsigned char* bbase = wb_t + (size_t)bn * 128 * 4096;   // 512KB slice

    f32x4 acc[8];
    #pragma unroll
    for (int j = 0; j < 8; j++) acc[j] = (f32x4)0.0f;

#define ISSUE(step, buf)                                                          \
    do {                                                                          \
        gl16(abase + (size_t)(step) * 4096 + tid * 16, &Ab[buf][tid * 16]);       \
        gl16(bbase + (size_t)(step) * 8192 + tid * 16, &Bb[buf][tid * 16]);       \
        gl16(bbase + (size_t)(step) * 8192 + (256 + tid) * 16,                    \
             &Bb[buf][(256 + tid) * 16]);                                         \
    } while (0)

    ISSUE(0, 0);
    ISSUE(1, 1);

    for (int t = 0; t < 64; t++) {
        const int buf = t & 3;
        if (t <= 61) {
            ISSUE(t + 2, (t + 2) & 3);
            asm volatile("s_waitcnt vmcnt(6)" ::: "memory");   // step t's 3 loads done
        } else if (t == 62) {
            asm volatile("s_waitcnt vmcnt(3)" ::: "memory");
        } else {
            asm volatile("s_waitcnt vmcnt(0)" ::: "memory");
        }
        __builtin_amdgcn_s_barrier();
        __builtin_amdgcn_sched_barrier(0);

        #pragma unroll
        for (int j = 0; j < 2; j++) {
            long af = *(const long*)&Ab[buf][j * 2048 + (w * 16 + arow) * 32 + kgs * 8];
            #pragma unroll
            for (int nf = 0; nf < 8; nf++) {
                long bf = *(const long*)&Bb[buf][j * 4096 + (nf * 16 + arow) * 32 + kgs * 8];
                acc[nf] = __builtin_amdgcn_mfma_f32_16x16x32_fp8_fp8(af, bf, acc[nf], 0, 0, 0);
            }
        }
    }
#undef ISSUE

    // epilogue: EXACT relu over full-K h, dot W2 over this block's 128 cols.
    // C/D layout (m89): col = lane&15 (N idx), row = (lane>>4)*4 + i (M idx)
    float p[4] = {0.0f, 0.0f, 0.0f, 0.0f};
    #pragma unroll
    for (int nf = 0; nf < 8; nf++) {
        const int n = bn * 128 + nf * 16 + arow;
        const float bb = b1[n], ww = W2[n];
        #pragma unroll
        for (int i = 0; i < 4; i++) {
            float h = acc[nf][i] * 0.015625f + bb;   // undo W1*64 scale
            if (h > 0.0f) p[i] += h * ww;
        }
    }
    #pragma unroll
    for (int i = 0; i < 4; i++) {
        #pragma unroll
        for (int o = 1; o < 16; o <<= 1) p[i] += __shfl_xor(p[i], o, 64);
        if (arow == 0) {
            const int row = bm * 64 + w * 16 + kg * 4 + i;
            plogit[(size_t)row * 8 + bn] = p[i];     // unique writer -> plain store
        }
    }
}

// ---------------- k1b: per-row logit (sum 8 exact partials) -> sigmoid -> k
__global__ __launch_bounds__(256) void k1b_k(const float* __restrict__ plogit,
                                             const float* __restrict__ b2,
                                             int* __restrict__ k_arr,
                                             float* __restrict__ sp_arr)
{
    int row = blockIdx.x * 256 + threadIdx.x;
    float lg = 0.0f;
    #pragma unroll
    for (int t = 0; t < 8; t++) lg += plogit[(size_t)row * 8 + t];
    double s  = 1.0 / (1.0 + exp(-(double)(lg + b2[0])));
    double sp = 0.05 + 0.25 * s;
    int k = (int)rint(4096.0 * (1.0 - sp));
    if (k < 1) k = 1;
    if (k > 4096) k = 4096;
    k_arr[row] = k;
    sp_arr[row] = (float)sp;
}

// ---------------- k2: per-row radix-select threshold + all big outputs
__global__ __launch_bounds__(256) void k2_row(const float* __restrict__ x,
                                              const int* __restrict__ k_arr,
                                              const float* __restrict__ sp_arr,
                                              float* __restrict__ out_sparse,
                                              float* __restrict__ out_mask,
                                              float* __restrict__ out_spars,
                                              float* __restrict__ out_actual,
                                              double* __restrict__ l1rows)
{
    __shared__ unsigned bits[4096];
    __shared__ unsigned hist[256];
    __shared__ unsigned wsum[4];
    __shared__ int cnt_w[4];
    __shared__ double l1_w[4];
    __shared__ int sel_s;
    __shared__ unsigned selexc_s;

    const int row = blockIdx.x;
    const int tid = threadIdx.x;
    const int lane = tid & 63, wid = tid >> 6;
    const float* xr = x + (size_t)row * 4096;

    for (int i = tid; i < 1024; i += 256) {
        uint4 v = ((const uint4*)xr)[i];
        bits[i * 4 + 0] = v.x;
        bits[i * 4 + 1] = v.y;
        bits[i * 4 + 2] = v.z;
        bits[i * 4 + 3] = v.w;
    }
    if (tid == 0) out_spars[row] = sp_arr[row];
    __syncthreads();

    int krem = k_arr[row];
    unsigned prefix = 0;
    for (int pass = 0; pass < 4; pass++) {
        int shift = 24 - pass * 8;
        hist[tid] = 0;
        __syncthreads();
        for (int i = tid; i < 4096; i += 256) {
            unsigned a = bits[i] & 0x7fffffffu;
            bool ok = (pass == 0) || ((a >> (shift + 8)) == prefix);
            if (ok) atomicAdd(&hist[(a >> shift) & 255u], 1u);
        }
        __syncthreads();
        unsigned v = hist[tid];
        unsigned sc = v;
        #pragma unroll
        for (int o = 1; o < 64; o <<= 1) {
            unsigned n = __shfl_up(sc, o, 64);
            if (lane >= o) sc += n;
        }
        if (lane == 63) wsum[wid] = sc;
        __syncthreads();
        unsigned off = 0;
        for (int ww = 0; ww < wid; ww++) off += wsum[ww];
        sc += off;
        unsigned exc = sc - v;
        if ((int)sc >= krem && (int)exc < krem) { sel_s = tid; selexc_s = exc; }
        __syncthreads();
        prefix = (prefix << 8) | (unsigned)sel_s;
        krem -= (int)selexc_s;
        __syncthreads();
    }
    const unsigned thr = prefix;   // bit pattern of kth smallest |x|

    int cnt = 0;
    double l1 = 0.0;
    float* os = out_sparse + (size_t)row * 4096;
    float* om = out_mask + (size_t)row * 4096;
    for (int i = tid; i < 1024; i += 256) {
        float4 sv, mv;
        #pragma unroll
        for (int j = 0; j < 4; j++) {
            unsigned b = bits[i * 4 + j];
            unsigned a = b & 0x7fffffffu;
            bool m = a > thr;
            (&sv.x)[j] = m ? __uint_as_float(b) : 0.0f;
            (&mv.x)[j] = m ? 1.0f : 0.0f;
            if (m) { cnt++; l1 += (double)__uint_as_float(a); }
        }
        ((float4*)os)[i] = sv;
        ((float4*)om)[i] = mv;
    }
    #pragma unroll
    for (int o = 32; o > 0; o >>= 1) {
        cnt += __shfl_down(cnt, o, 64);
        l1  += __shfl_down(l1,  o, 64);
    }
    if (lane == 0) { cnt_w[wid] = cnt; l1_w[wid] = l1; }
    __syncthreads();
    if (tid == 0) {
        int c    = cnt_w[0] + cnt_w[1] + cnt_w[2] + cnt_w[3];
        double l = l1_w[0] + l1_w[1] + l1_w[2] + l1_w[3];
        out_actual[row] = (float)c / 4096.0f;
        l1rows[row] = l;
    }
}

// ---------------- k3: deterministic l1 mean (f64), 1024 threads
__global__ __launch_bounds__(1024) void k3_l1(const double* __restrict__ l1rows,
                                              float* __restrict__ out_l1)
{
    __shared__ double sm[1024];
    int tid = threadIdx.x;
    double s = l1rows[tid] + l1rows[tid + 1024] + l1rows[tid + 2048] + l1rows[tid + 3072];
    sm[tid] = s;
    __syncthreads();
    for (int st = 512; st > 0; st >>= 1) {
        if (tid < st) sm[tid] += sm[tid + st];
        __syncthreads();
    }
    if (tid == 0) out_l1[0] = (float)(sm[0] / 4096.0);
}

extern "C" void kernel_launch(void* const* d_in, const int* in_sizes, int n_in,
                              void* d_out, int out_size, void* d_ws, size_t ws_size,
                              hipStream_t stream)
{
    const float* x  = (const float*)d_in[0];
    const float* W1 = (const float*)d_in[1];
    const float* b1 = (const float*)d_in[2];
    const float* W2 = (const float*)d_in[3];
    const float* b2 = (const float*)d_in[4];

    float* out        = (float*)d_out;
    float* out_sparse = out;                       // [4096,4096]
    float* out_mask   = out + 16777216;            // [4096,4096]
    float* out_spars  = out + 33554432;            // [4096,1]
    float* out_actual = out + 33558528;            // [4096]
    float* out_l1     = out + 33562624;            // [1]

    // big scratch inside d_out (fully consumed by k1est before k2 writes)
    unsigned char* xa_t = (unsigned char*)(out);             // 16MB fp8
    unsigned char* wb_t = (unsigned char*)(out + 4194304);   // 4MB fp8

    // small hot arrays in d_ws (read by k1b/k2/k3 -> must not alias outputs)
    char* ws = (char*)d_ws;
    float*  plogit = (float*)(ws);             // 128KB [4096][8]
    int*    k_arr  = (int*)(ws + 131072);      // 16KB
    float*  sp_arr = (float*)(ws + 147456);    // 16KB
    double* l1rows = (double*)(ws + 163840);   // 32KB

    k0a_cvtx<<<dim3(64, 8), 256, 0, stream>>>(x, xa_t);
    k0b_cvtw<<<1024, 256, 0, stream>>>(W1, wb_t);
    k1est<<<512, 256, 0, stream>>>(xa_t, wb_t, b1, W2, plogit);
    k1b_k<<<16, 256, 0, stream>>>(plogit, b2, k_arr, sp_arr);
    k2_row<<<4096, 256, 0, stream>>>(x, k_arr, sp_arr, out_sparse, out_mask,
                                     out_spars, out_actual, l1rows);
    k3_l1<<<1, 1024, 0, stream>>>(l1rows, out_l1);
}

// Round 10
// 126.166 us; speedup vs baseline: 1.5050x; 1.1354x over previous
//
#include <hip/hip_runtime.h>
#include <hip/hip_fp8.h>

typedef __attribute__((ext_vector_type(4))) float f32x4;

// ---- d_out scratch (float offsets), consumed by k1est before k2 overwrites:
//   xa_t fp8[16777216B] -> floats [0, 4194304)        tiled [64 bm][128 kt][64 r][32 k] swz
//   wb_t fp8[ 4194304B] -> floats [4194304, 5242880)  tiled [ 8 bn][128 kt][128 n][32 k] swz (W1*64)
// ---- d_ws layout (bytes):
//   plogit f32[4096*8]  [0, 131072)      exact relu'd N-partials (unique writer)
//   k_arr  int[4096]    [131072, 147456)
//   sp_arr f32[4096]    [147456, 163840)
//   l1rows f64[4096]    [163840, 196608)

__device__ __forceinline__ unsigned char f2fp8(float f) {
    return (unsigned char)__hip_cvt_float_to_fp8(f, __HIP_SATFINITE, __HIP_E4M3);
}

__device__ __forceinline__ void gl16(const void* g, void* l) {
    __builtin_amdgcn_global_load_lds(
        (const __attribute__((address_space(1))) void*)g,
        (__attribute__((address_space(3))) void*)l, 16, 0, 0);
}

// ---------------- k0a: x (fp32 [4096][4096]) -> xa_t (fp8 e4m3, 64-row K-tiled + swz)
__global__ __launch_bounds__(256) void k0a_cvtx(const float* __restrict__ x,
                                                unsigned char* __restrict__ xa_t)
{
    const int bm = blockIdx.x;                // 0..63 (64-row group)
    const int ktbase = blockIdx.y * 16;       // 8 y-blocks x 16 kt
    const int t = threadIdx.x;
    const int rr = t >> 2, q = t & 3;         // row 0..63, k-oct 0..3
    const int kgp = q ^ ((rr >> 1) & 3);
    const size_t rowoff = (size_t)(bm * 64 + rr) * 4096;

    #pragma unroll
    for (int i = 0; i < 16; i++) {
        const int kt = ktbase + i;
        const float* src = x + rowoff + kt * 32 + q * 8;
        float4 v0 = *(const float4*)src;
        float4 v1 = *(const float4*)(src + 4);
        union { unsigned char c[8]; uint2 u; } o;
        o.c[0] = f2fp8(v0.x); o.c[1] = f2fp8(v0.y);
        o.c[2] = f2fp8(v0.z); o.c[3] = f2fp8(v0.w);
        o.c[4] = f2fp8(v1.x); o.c[5] = f2fp8(v1.y);
        o.c[6] = f2fp8(v1.z); o.c[7] = f2fp8(v1.w);
        *(uint2*)(xa_t + ((size_t)(bm * 128 + kt) * 64 + rr) * 32 + kgp * 8) = o.u;
    }
}

// ---------------- k0b: W1 [4096][1024] fp32 -> wb_t (fp8 of 64*W1, transposed tiled + swz)
__global__ __launch_bounds__(256) void k0b_cvtw(const float* __restrict__ W1,
                                                unsigned char* __restrict__ wb_t)
{
    __shared__ float ls[32][128];
    const int bx = blockIdx.x;                // 1024 = 8 bn x 128 kt
    const int bn = bx >> 7, kt = bx & 127;
    const int t = threadIdx.x;

    #pragma unroll
    for (int i = 0; i < 4; i++) {
        int s = t + i * 256;                  // 1024 float4 slots
        int r = s >> 5, c4 = s & 31;
        *(float4*)&ls[r][c4 * 4] =
            *(const float4*)(W1 + (size_t)(kt * 32 + r) * 1024 + bn * 128 + c4 * 4);
    }
    __syncthreads();

    const int n = t >> 1, half = t & 1;
    #pragma unroll
    for (int kg2 = 0; kg2 < 2; kg2++) {
        const int kg = half * 2 + kg2;
        const int kgp = kg ^ ((n >> 1) & 3);
        union { unsigned char c[8]; uint2 u; } o;
        #pragma unroll
        for (int j = 0; j < 8; j++) o.c[j] = f2fp8(ls[kg * 8 + j][n] * 64.0f);
        *(uint2*)(wb_t + (size_t)(bn * 128 + kt) * 4096 + n * 32 + kgp * 8) = o.u;
    }
}

// ---------------- k1est: fp8 MFMA, BM=64 x BN=128, FULL K (exact relu), N-split partials.
// Quad-buffered LDS, 2-ahead prefetch, counted vmcnt(6) (T3+T4). Unchanged from R9.
__global__ __launch_bounds__(256, 2) void k1est(const unsigned char* __restrict__ xa_t,
                                                const unsigned char* __restrict__ wb_t,
                                                const float* __restrict__ b1,
                                                const float* __restrict__ W2,
                                                float* __restrict__ plogit)
{
    __shared__ alignas(16) unsigned char Ab[4][4096];
    __shared__ alignas(16) unsigned char Bb[4][8192];

    const int bid = blockIdx.x;                      // 512 blocks
    const int wgid = (bid & 7) * 64 + (bid >> 3);    // bijective, XCD-chunked
    const int bn = wgid >> 6, bm = wgid & 63;
    const int tid = threadIdx.x;
    const int l = tid & 63, w = tid >> 6;
    const int arow = l & 15, kg = l >> 4;
    const int kgs = kg ^ ((arow >> 1) & 3);

    const unsigned char* abase = xa_t + (size_t)bm * 128 * 2048;
    const unsigned char* bbase = wb_t + (size_t)bn * 128 * 4096;

    f32x4 acc[8];
    #pragma unroll
    for (int j = 0; j < 8; j++) acc[j] = (f32x4)0.0f;

#define ISSUE(step, buf)                                                          \
    do {                                                                          \
        gl16(abase + (size_t)(step) * 4096 + tid * 16, &Ab[buf][tid * 16]);       \
        gl16(bbase + (size_t)(step) * 8192 + tid * 16, &Bb[buf][tid * 16]);       \
        gl16(bbase + (size_t)(step) * 8192 + (256 + tid) * 16,                    \
             &Bb[buf][(256 + tid) * 16]);                                         \
    } while (0)

    ISSUE(0, 0);
    ISSUE(1, 1);

    for (int t = 0; t < 64; t++) {
        const int buf = t & 3;
        if (t <= 61) {
            ISSUE(t + 2, (t + 2) & 3);
            asm volatile("s_waitcnt vmcnt(6)" ::: "memory");
        } else if (t == 62) {
            asm volatile("s_waitcnt vmcnt(3)" ::: "memory");
        } else {
            asm volatile("s_waitcnt vmcnt(0)" ::: "memory");
        }
        __builtin_amdgcn_s_barrier();
        __builtin_amdgcn_sched_barrier(0);

        #pragma unroll
        for (int j = 0; j < 2; j++) {
            long af = *(const long*)&Ab[buf][j * 2048 + (w * 16 + arow) * 32 + kgs * 8];
            #pragma unroll
            for (int nf = 0; nf < 8; nf++) {
                long bf = *(const long*)&Bb[buf][j * 4096 + (nf * 16 + arow) * 32 + kgs * 8];
                acc[nf] = __builtin_amdgcn_mfma_f32_16x16x32_fp8_fp8(af, bf, acc[nf], 0, 0, 0);
            }
        }
    }
#undef ISSUE

    float p[4] = {0.0f, 0.0f, 0.0f, 0.0f};
    #pragma unroll
    for (int nf = 0; nf < 8; nf++) {
        const int n = bn * 128 + nf * 16 + arow;
        const float bb = b1[n], ww = W2[n];
        #pragma unroll
        for (int i = 0; i < 4; i++) {
            float h = acc[nf][i] * 0.015625f + bb;
            if (h > 0.0f) p[i] += h * ww;
        }
    }
    #pragma unroll
    for (int i = 0; i < 4; i++) {
        #pragma unroll
        for (int o = 1; o < 16; o <<= 1) p[i] += __shfl_xor(p[i], o, 64);
        if (arow == 0) {
            const int row = bm * 64 + w * 16 + kg * 4 + i;
            plogit[(size_t)row * 8 + bn] = p[i];
        }
    }
}

// ---------------- k1b: per-row logit (sum 8 exact partials) -> sigmoid -> k
__global__ __launch_bounds__(256) void k1b_k(const float* __restrict__ plogit,
                                             const float* __restrict__ b2,
                                             int* __restrict__ k_arr,
                                             float* __restrict__ sp_arr)
{
    int row = blockIdx.x * 256 + threadIdx.x;
    float lg = 0.0f;
    #pragma unroll
    for (int t = 0; t < 8; t++) lg += plogit[(size_t)row * 8 + t];
    double s  = 1.0 / (1.0 + exp(-(double)(lg + b2[0])));
    double sp = 0.05 + 0.25 * s;
    int k = (int)rint(4096.0 * (1.0 - sp));
    if (k < 1) k = 1;
    if (k > 4096) k = 4096;
    k_arr[row] = k;
    sp_arr[row] = (float)sp;
}

// ---------------- k2: per-row select + outputs. Radix select 11+8+8+4 bits:
// pass 0 = 2048 log-spaced bins (exp + 3 mantissa bits) -> max-bin ~200 for
// normal data (was ~2500 with 8-bit exponent-only bins = LDS same-address
// atomic serialization, 1.15e7 conflicts). Passes 1-3 touch ~200 elements.
__global__ __launch_bounds__(256) void k2_row(const float* __restrict__ x,
                                              const int* __restrict__ k_arr,
                                              const float* __restrict__ sp_arr,
                                              float* __restrict__ out_sparse,
                                              float* __restrict__ out_mask,
                                              float* __restrict__ out_spars,
                                              float* __restrict__ out_actual,
                                              double* __restrict__ l1rows)
{
    __shared__ unsigned bits[4096];
    __shared__ unsigned hist[2048];
    __shared__ unsigned wsum[4];
    __shared__ int cnt_w[4];
    __shared__ double l1_w[4];
    __shared__ unsigned sel_s, selexc_s;

    const int row = blockIdx.x;
    const int tid = threadIdx.x;
    const int lane = tid & 63, wid = tid >> 6;
    const float* xr = x + (size_t)row * 4096;

    for (int i = tid; i < 1024; i += 256) {
        uint4 v = ((const uint4*)xr)[i];
        bits[i * 4 + 0] = v.x;
        bits[i * 4 + 1] = v.y;
        bits[i * 4 + 2] = v.z;
        bits[i * 4 + 3] = v.w;
    }
    if (tid == 0) out_spars[row] = sp_arr[row];

    int krem = k_arr[row];
    unsigned prefix = 0;

    // ---- pass 0: 11-bit bins (bits 30:20)
    for (int i = tid; i < 2048; i += 256) hist[i] = 0;
    __syncthreads();
    for (int i = tid; i < 4096; i += 256)
        atomicAdd(&hist[(bits[i] & 0x7fffffffu) >> 20], 1u);
    __syncthreads();
    {
        const unsigned base = tid * 8;
        unsigned bl[8];
        unsigned v = 0;
        #pragma unroll
        for (int j = 0; j < 8; j++) { bl[j] = hist[base + j]; v += bl[j]; }
        unsigned sc = v;
        #pragma unroll
        for (int o = 1; o < 64; o <<= 1) {
            unsigned n = __shfl_up(sc, o, 64);
            if (lane >= o) sc += n;
        }
        if (lane == 63) wsum[wid] = sc;
        __syncthreads();
        unsigned off = 0;
        for (int ww = 0; ww < wid; ww++) off += wsum[ww];
        sc += off;
        unsigned exc = sc - v;
        if ((int)sc >= krem && (int)exc < krem) {
            unsigned run = exc;
            #pragma unroll
            for (int j = 0; j < 8; j++) {
                if ((int)run < krem && (int)(run + bl[j]) >= krem) {
                    sel_s = base + j; selexc_s = run;
                }
                run += bl[j];
            }
        }
        __syncthreads();
        prefix = sel_s;
        krem -= (int)selexc_s;
        __syncthreads();
    }

    // ---- passes 1-3: 8/8/4 bits among prefix-matched elements
    #pragma unroll
    for (int p = 0; p < 3; p++) {
        const int shift = (p == 0) ? 12 : (p == 1) ? 4 : 0;
        const int width = (p == 2) ? 4 : 8;
        const int nb = 1 << width;
        const int topshift = shift + width;
        if (tid < nb) hist[tid] = 0;
        __syncthreads();
        for (int i = tid; i < 4096; i += 256) {
            unsigned a = bits[i] & 0x7fffffffu;
            if ((a >> topshift) == prefix)
                atomicAdd(&hist[(a >> shift) & (nb - 1)], 1u);
        }
        __syncthreads();
        unsigned v = (tid < nb) ? hist[tid] : 0;
        unsigned sc = v;
        #pragma unroll
        for (int o = 1; o < 64; o <<= 1) {
            unsigned n = __shfl_up(sc, o, 64);
            if (lane >= o) sc += n;
        }
        if (lane == 63) wsum[wid] = sc;
        __syncthreads();
        unsigned off = 0;
        for (int ww = 0; ww < wid; ww++) off += wsum[ww];
        sc += off;
        unsigned exc = sc - v;
        if ((int)sc >= krem && (int)exc < krem) { sel_s = (unsigned)tid; selexc_s = exc; }
        __syncthreads();
        prefix = (prefix << width) | sel_s;
        krem -= (int)selexc_s;
        __syncthreads();
    }
    const unsigned thr = prefix;   // bit pattern of kth smallest |x| (31 bits)

    int cnt = 0;
    double l1 = 0.0;
    float* os = out_sparse + (size_t)row * 4096;
    float* om = out_mask + (size_t)row * 4096;
    for (int i = tid; i < 1024; i += 256) {
        float4 sv, mv;
        #pragma unroll
        for (int j = 0; j < 4; j++) {
            unsigned b = bits[i * 4 + j];
            unsigned a = b & 0x7fffffffu;
            bool m = a > thr;
            (&sv.x)[j] = m ? __uint_as_float(b) : 0.0f;
            (&mv.x)[j] = m ? 1.0f : 0.0f;
            if (m) { cnt++; l1 += (double)__uint_as_float(a); }
        }
        ((float4*)os)[i] = sv;
        ((float4*)om)[i] = mv;
    }
    #pragma unroll
    for (int o = 32; o > 0; o >>= 1) {
        cnt += __shfl_down(cnt, o, 64);
        l1  += __shfl_down(l1,  o, 64);
    }
    if (lane == 0) { cnt_w[wid] = cnt; l1_w[wid] = l1; }
    __syncthreads();
    if (tid == 0) {
        int c    = cnt_w[0] + cnt_w[1] + cnt_w[2] + cnt_w[3];
        double l = l1_w[0] + l1_w[1] + l1_w[2] + l1_w[3];
        out_actual[row] = (float)c / 4096.0f;
        l1rows[row] = l;
    }
}

// ---------------- k3: deterministic l1 mean (f64), 1024 threads
__global__ __launch_bounds__(1024) void k3_l1(const double* __restrict__ l1rows,
                                              float* __restrict__ out_l1)
{
    __shared__ double sm[1024];
    int tid = threadIdx.x;
    double s = l1rows[tid] + l1rows[tid + 1024] + l1rows[tid + 2048] + l1rows[tid + 3072];
    sm[tid] = s;
    __syncthreads();
    for (int st = 512; st > 0; st >>= 1) {
        if (tid < st) sm[tid] += sm[tid + st];
        __syncthreads();
    }
    if (tid == 0) out_l1[0] = (float)(sm[0] / 4096.0);
}

extern "C" void kernel_launch(void* const* d_in, const int* in_sizes, int n_in,
                              void* d_out, int out_size, void* d_ws, size_t ws_size,
                              hipStream_t stream)
{
    const float* x  = (const float*)d_in[0];
    const float* W1 = (const float*)d_in[1];
    const float* b1 = (const float*)d_in[2];
    const float* W2 = (const float*)d_in[3];
    const float* b2 = (const float*)d_in[4];

    float* out        = (float*)d_out;
    float* out_sparse = out;                       // [4096,4096]
    float* out_mask   = out + 16777216;            // [4096,4096]
    float* out_spars  = out + 33554432;            // [4096,1]
    float* out_actual = out + 33558528;            // [4096]
    float* out_l1     = out + 33562624;            // [1]

    // big scratch inside d_out (fully consumed by k1est before k2 writes)
    unsigned char* xa_t = (unsigned char*)(out);             // 16MB fp8
    unsigned char* wb_t = (unsigned char*)(out + 4194304);   // 4MB fp8

    // small hot arrays in d_ws (read by k1b/k2/k3 -> must not alias outputs)
    char* ws = (char*)d_ws;
    float*  plogit = (float*)(ws);             // 128KB [4096][8]
    int*    k_arr  = (int*)(ws + 131072);      // 16KB
    float*  sp_arr = (float*)(ws + 147456);    // 16KB
    double* l1rows = (double*)(ws + 163840);   // 32KB

    k0a_cvtx<<<dim3(64, 8), 256, 0, stream>>>(x, xa_t);
    k0b_cvtw<<<1024, 256, 0, stream>>>(W1, wb_t);
    k1est<<<512, 256, 0, stream>>>(xa_t, wb_t, b1, W2, plogit);
    k1b_k<<<16, 256, 0, stream>>>(plogit, b2, k_arr, sp_arr);
    k2_row<<<4096, 256, 0, stream>>>(x, k_arr, sp_arr, out_sparse, out_mask,
                                     out_spars, out_actual, l1rows);
    k3_l1<<<1, 1024, 0, stream>>>(l1rows, out_l1);
}